// Round 4
// baseline (858.546 us; speedup 1.0000x reference)
//
#include <hip/hip_runtime.h>
#include <hip/hip_bf16.h>
#include <math.h>

#define NGRAPHS 256
#define BSHIFT 8
#define NBUCK 512    // 256-node buckets; covers N up to 131072
#define NSORT 256    // blocks for bhist/bscatter (256 threads each)
#define LSTAT 512    // lin_stats blocks
#define SMASK 0x00FFFFFFu  // low 24 bits = src (N < 2^24)

__device__ __forceinline__ float bf2f(unsigned short u) {
    return __uint_as_float((unsigned)u << 16);
}
__device__ __forceinline__ unsigned short f2bf(float f) {
    unsigned u = __float_as_uint(f);
    unsigned r = (u + 0x7FFFu + ((u >> 16) & 1u)) >> 16;  // RNE
    return (unsigned short)r;
}

// ---------------- bucket histogram (+ zero-init of pooled/cnt region: replaces hipMemsetAsync) ----------------
__global__ __launch_bounds__(256) void k_bhist(const int* __restrict__ dst, int* __restrict__ hmat, int E,
                                               float* __restrict__ zbase, int zwords) {
    if (blockIdx.x == 0) {
        for (int i = threadIdx.x; i < zwords; i += 256) zbase[i] = 0.f;
    }
    __shared__ int hist[NBUCK];
    for (int i = threadIdx.x; i < NBUCK; i += 256) hist[i] = 0;
    __syncthreads();
    int chunk = (E + NSORT - 1) / NSORT;
    int lo = blockIdx.x * chunk;
    int hi = lo + chunk; if (hi > E) hi = E;
    for (int i = lo + threadIdx.x; i < hi; i += 256) {
        int d = __builtin_nontemporal_load(dst + i);
        atomicAdd(&hist[d >> BSHIFT], 1);
    }
    __syncthreads();
    for (int i = threadIdx.x; i < NBUCK; i += 256)
        hmat[(size_t)blockIdx.x * NBUCK + i] = hist[i];  // coalesced dump
}

// ---------------- merged column scan + bucket scan: one block, 512 threads ----------------
__global__ __launch_bounds__(512) void k_scan(int* __restrict__ hmat, int* __restrict__ bstart) {
    __shared__ int s[512];
    int col = threadIdx.x;  // one thread per bucket
    int run = 0;
#pragma unroll 4
    for (int r = 0; r < NSORT; r++) {
        int v = hmat[(size_t)r * NBUCK + col];   // coalesced across threads
        hmat[(size_t)r * NBUCK + col] = run;
        run += v;
    }
    s[col] = run;
    __syncthreads();
    for (int off = 1; off < 512; off <<= 1) {
        int t = (col >= off) ? s[col - off] : 0;
        __syncthreads();
        s[col] += t;
        __syncthreads();
    }
    bstart[col] = s[col] - run;  // exclusive
    if (col == 511) bstart[NBUCK] = s[511];
}

// ---------------- scatter into bucket-ordered ebuf via precomputed LDS cursors ----------------
// pack: word = src | (dst&255)<<24
__global__ __launch_bounds__(256) void k_bscatter(const int* __restrict__ src, const int* __restrict__ dst,
                                                  const int* __restrict__ hmat, const int* __restrict__ bstart,
                                                  unsigned* __restrict__ ebuf, int E) {
    __shared__ int cur[NBUCK];
    for (int i = threadIdx.x; i < NBUCK; i += 256)
        cur[i] = bstart[i] + hmat[(size_t)blockIdx.x * NBUCK + i];
    __syncthreads();
    int chunk = (E + NSORT - 1) / NSORT;
    int lo = blockIdx.x * chunk;
    int hi = lo + chunk; if (hi > E) hi = E;
    for (int i = lo + threadIdx.x; i < hi; i += 256) {
        int d = __builtin_nontemporal_load(dst + i);
        int s = __builtin_nontemporal_load(src + i);
        int p = atomicAdd(&cur[d >> BSHIFT], 1);
        ebuf[p] = (unsigned)s | ((unsigned)(d & 255) << 24);
    }
}

// ---------------- per-bucket LDS counting sort (256 nodes) -> full CSR + row_start ----------------
__global__ __launch_bounds__(256) void k_sort2(const unsigned* __restrict__ ebuf, const int* __restrict__ bstart,
                                               int* __restrict__ csr, int* __restrict__ row_start, int N) {
    __shared__ int hist[256];
    __shared__ int sc[256];
    __shared__ int scur[256];
    int b = blockIdx.x;
    int e0 = bstart[b], e1 = bstart[b + 1];
    hist[threadIdx.x] = 0;
    __syncthreads();
    for (int i = e0 + threadIdx.x; i < e1; i += 256)
        atomicAdd(&hist[__builtin_nontemporal_load(ebuf + i) >> 24], 1);
    __syncthreads();
    // Hillis-Steele inclusive scan over 256 entries
    sc[threadIdx.x] = hist[threadIdx.x];
    __syncthreads();
    for (int off = 1; off < 256; off <<= 1) {
        int t = (threadIdx.x >= off) ? sc[threadIdx.x - off] : 0;
        __syncthreads();
        sc[threadIdx.x] += t;
        __syncthreads();
    }
    {
        int inc = sc[threadIdx.x];
        int ex = inc - hist[threadIdx.x];
        scur[threadIdx.x] = e0 + ex;
        int node = (b << BSHIFT) + threadIdx.x;
        if (node < N) row_start[node] = e0 + ex;
        if (node == N - 1) row_start[N] = e0 + inc;  // == E
    }
    __syncthreads();
    for (int i = e0 + threadIdx.x; i < e1; i += 256) {
        unsigned w = __builtin_nontemporal_load(ebuf + i);
        int p = atomicAdd(&scur[w >> 24], 1);
        csr[p] = (int)(w & SMASK);
    }
}

// ---------------- plain dense layer (layer-1 rel matmul 64->16, bf16 out), thread per (node,quad) ----------------
template <int CI, int CO>
__global__ __launch_bounds__(256) void k_lin_rel(const float* __restrict__ hrel, const float* __restrict__ w_rel,
                                                 unsigned short* __restrict__ outb, int N) {
    constexpr int QPR = CO / 4;
    __shared__ float s_rel[CI * CO];
    for (int i = threadIdx.x; i < CI * CO; i += 256) s_rel[i] = w_rel[i];
    __syncthreads();
    int t = blockIdx.x * 256 + threadIdx.x;
    int n = t / QPR;
    int c0 = (t % QPR) * 4;
    if (n >= N) return;
    float ar[CI];
    const float4* mp = (const float4*)(hrel + (size_t)n * CI);
#pragma unroll
    for (int i = 0; i < CI / 4; i++) {
        float4 v = mp[i];
        ar[4 * i + 0] = v.x; ar[4 * i + 1] = v.y; ar[4 * i + 2] = v.z; ar[4 * i + 3] = v.w;
    }
    float4 acc; acc.x = 0.f; acc.y = 0.f; acc.z = 0.f; acc.w = 0.f;
#pragma unroll
    for (int ci = 0; ci < CI; ci++) {
        float a = ar[ci];
        float4 w = *(const float4*)&s_rel[ci * CO + c0];
        acc.x += a * w.x; acc.y += a * w.y; acc.z += a * w.z; acc.w += a * w.w;
    }
    ushort4 o;
    o.x = f2bf(acc.x); o.y = f2bf(acc.y); o.z = f2bf(acc.z); o.w = f2bf(acc.w);
    *(ushort4*)(outb + (size_t)n * CO + c0) = o;
}

// ---------------- dense layer + fused BN-stats (partials + last-block finalize) ----------------
// grid-stride over (node,quad) elements with LSTAT blocks; c0 is constant per thread (QPR | stride).
template <int CI, int CO, bool HAS_REL, bool ADD_AGG, bool IN_BF16>
__global__ __launch_bounds__(256) void k_lin_stats(const void* __restrict__ hroot_v, const float* __restrict__ hrel,
                                                   const float* __restrict__ w_rel, const float* __restrict__ w_root,
                                                   const float* __restrict__ bias, const float* __restrict__ aggadd,
                                                   float* __restrict__ out, float* __restrict__ partials,
                                                   const float* __restrict__ g, const float* __restrict__ be,
                                                   float* __restrict__ stats, int* __restrict__ cnt,
                                                   float invN, int N) {
    constexpr int QPR = CO / 4;
    __shared__ float s_rel[HAS_REL ? CI * CO : 1];
    __shared__ float s_root[CI * CO];
    __shared__ float s_b[CO];
    __shared__ float part[4][2 * CO];
    __shared__ float red[128];
    __shared__ int is_last;
    if (HAS_REL)
        for (int i = threadIdx.x; i < CI * CO; i += 256) s_rel[i] = w_rel[i];
    for (int i = threadIdx.x; i < CI * CO; i += 256) s_root[i] = w_root[i];
    if (threadIdx.x < CO) s_b[threadIdx.x] = bias[threadIdx.x];
    __syncthreads();

    int total = N * QPR;
    float s0 = 0, s1 = 0, s2 = 0, s3 = 0, q0 = 0, q1 = 0, q2 = 0, q3 = 0;
    for (int i = blockIdx.x * 256 + threadIdx.x; i < total; i += LSTAT * 256) {
        int n = i / QPR;
        int c0 = (i % QPR) * 4;  // constant per thread across iterations

        float rr[CI];
        if (IN_BF16) {
            const ushort4* hp = (const ushort4*)((const unsigned short*)hroot_v + (size_t)n * CI);
#pragma unroll
            for (int k = 0; k < CI / 4; k++) {
                ushort4 v = hp[k];
                rr[4 * k + 0] = bf2f(v.x); rr[4 * k + 1] = bf2f(v.y);
                rr[4 * k + 2] = bf2f(v.z); rr[4 * k + 3] = bf2f(v.w);
            }
        } else {
            const float4* hp = (const float4*)((const float*)hroot_v + (size_t)n * CI);
#pragma unroll
            for (int k = 0; k < CI / 4; k++) {
                float4 v = hp[k];
                rr[4 * k + 0] = v.x; rr[4 * k + 1] = v.y; rr[4 * k + 2] = v.z; rr[4 * k + 3] = v.w;
            }
        }
        float ar[HAS_REL ? CI : 1];
        if (HAS_REL) {
            const float4* mp = (const float4*)(hrel + (size_t)n * CI);
#pragma unroll
            for (int k = 0; k < CI / 4; k++) {
                float4 v = mp[k];
                ar[4 * k + 0] = v.x; ar[4 * k + 1] = v.y; ar[4 * k + 2] = v.z; ar[4 * k + 3] = v.w;
            }
        }
        float4 acc = *(const float4*)&s_b[c0];
        if (ADD_AGG) {
            float4 v = ((const float4*)aggadd)[i];
            acc.x += v.x; acc.y += v.y; acc.z += v.z; acc.w += v.w;
        }
#pragma unroll
        for (int ci = 0; ci < CI; ci++) {
            float hv = rr[ci];
            float4 w = *(const float4*)&s_root[ci * CO + c0];
            acc.x += hv * w.x; acc.y += hv * w.y; acc.z += hv * w.z; acc.w += hv * w.w;
            if (HAS_REL) {
                float a = ar[ci];
                float4 wr = *(const float4*)&s_rel[ci * CO + c0];
                acc.x += a * wr.x; acc.y += a * wr.y; acc.z += a * wr.z; acc.w += a * wr.w;
            }
        }
        ((float4*)out)[i] = acc;
        s0 += acc.x; q0 += acc.x * acc.x;
        s1 += acc.y; q1 += acc.y * acc.y;
        s2 += acc.z; q2 += acc.z * acc.z;
        s3 += acc.w; q3 += acc.w * acc.w;
    }
#pragma unroll
    for (int off = QPR; off < 64; off <<= 1) {
        s0 += __shfl_xor(s0, off, 64); q0 += __shfl_xor(q0, off, 64);
        s1 += __shfl_xor(s1, off, 64); q1 += __shfl_xor(q1, off, 64);
        s2 += __shfl_xor(s2, off, 64); q2 += __shfl_xor(q2, off, 64);
        s3 += __shfl_xor(s3, off, 64); q3 += __shfl_xor(q3, off, 64);
    }
    int lane = threadIdx.x & 63;
    int w = threadIdx.x >> 6;
    if (lane < QPR) {
        int cq = lane * 4;
        part[w][cq + 0] = s0; part[w][CO + cq + 0] = q0;
        part[w][cq + 1] = s1; part[w][CO + cq + 1] = q1;
        part[w][cq + 2] = s2; part[w][CO + cq + 2] = q2;
        part[w][cq + 3] = s3; part[w][CO + cq + 3] = q3;
    }
    __syncthreads();
    if (threadIdx.x < 2 * CO) {
        float v = part[0][threadIdx.x] + part[1][threadIdx.x] + part[2][threadIdx.x] + part[3][threadIdx.x];
        partials[blockIdx.x * (2 * CO) + threadIdx.x] = v;
    }
    // last-block finalize
    __threadfence();
    if (threadIdx.x == 0) is_last = (atomicAdd(cnt, 1) == LSTAT - 1);
    __syncthreads();
    if (!is_last) return;
    __threadfence();
    int c = threadIdx.x;
    if (c < 2 * CO) {
        float s = 0.f;
#pragma unroll 8
        for (int b = 0; b < LSTAT; b++) s += partials[b * 2 * CO + c];
        red[c] = s;
    }
    __syncthreads();
    if (c < CO) {
        float mean = red[c] * invN;
        float var = red[CO + c] * invN - mean * mean;
        float sc = g[c] * rsqrtf(var + 1e-5f);
        stats[128 + c] = sc;
        stats[192 + c] = be[c] - mean * sc;
    }
}

// ---------------- gather: LDS-staged csr + predicated parallel batches (clamp to batch base) ----------------
// One wave per node; block of 4 waves stages its 4 contiguous csr rows into LDS once.
// All 4 loads of a batch issue back-to-back (no serial remainder); out-of-range slots clamp to sbuf[j0]
// -> at most 1 wasted (duplicated) line per tail batch.
#define GCHUNK 1024
template <int C>
__global__ __launch_bounds__(256) void k_gather(const unsigned short* __restrict__ h,
                                                const int* __restrict__ row_start,
                                                const int* __restrict__ csr, float* __restrict__ agg, int N) {
    constexpr int LPR = C / 4;        // lanes per edge-line
    constexpr int EPP = 64 / LPR;     // edge slots per wave instruction
    constexpr int BATCH = 4 * EPP;    // 4 loads in flight per batch
    __shared__ int sbuf[GCHUNK];
    int lane = threadIdx.x & 63;
    int w = threadIdx.x >> 6;
    int nb = blockIdx.x * 4;          // first node of this block
    int wid = nb + w;
    bool act = wid < N;
    int nb_end = nb + 4; if (nb_end > N) nb_end = N;
    int eb0 = row_start[nb];
    int eb1 = row_start[nb_end];
    int r0 = act ? row_start[wid] : 0;
    int r1 = act ? row_start[wid + 1] : 0;
    int es = lane / LPR;              // edge slot
    int cq = (lane % LPR) * 4;        // channel quad

    float a0 = 0.f, a1 = 0.f, a2 = 0.f, a3 = 0.f;
    for (int base = eb0; base < eb1; base += GCHUNK) {
        int len = eb1 - base; if (len > GCHUNK) len = GCHUNK;
        __syncthreads();
        for (int i = threadIdx.x; i < len; i += 256)
            sbuf[i] = __builtin_nontemporal_load(csr + base + i);
        __syncthreads();
        if (act) {
            int lo = (r0 > base ? r0 : base) - base;
            int hiv = r1 < base + len ? r1 : base + len;
            int hi = hiv - base;
#pragma unroll 2
            for (int j0 = lo; j0 < hi; j0 += BATCH) {
                int s[4]; bool p[4];
#pragma unroll
                for (int u = 0; u < 4; u++) {
                    int j = j0 + u * EPP + es;
                    p[u] = j < hi;
                    s[u] = sbuf[p[u] ? j : j0];  // clamp to batch base: single duplicated line
                }
                ushort4 v[4];
#pragma unroll
                for (int u = 0; u < 4; u++)
                    v[u] = *(const ushort4*)(h + (size_t)s[u] * C + cq);
#pragma unroll
                for (int u = 0; u < 4; u++) {
                    if (p[u]) {
                        a0 += bf2f(v[u].x); a1 += bf2f(v[u].y);
                        a2 += bf2f(v[u].z); a3 += bf2f(v[u].w);
                    }
                }
            }
        }
    }
#pragma unroll
    for (int off = LPR; off < 64; off <<= 1) {
        a0 += __shfl_xor(a0, off, 64);
        a1 += __shfl_xor(a1, off, 64);
        a2 += __shfl_xor(a2, off, 64);
        a3 += __shfl_xor(a3, off, 64);
    }
    if (act && lane < LPR) {
        int deg = r1 - r0;
        float rec = 1.0f / (float)(deg > 0 ? deg : 1);
        float4 o; o.x = a0 * rec; o.y = a1 * rec; o.z = a2 * rec; o.w = a3 * rec;
        *(float4*)(agg + (size_t)wid * C + cq) = o;
    }
}

// ---------------- BN apply + ELU: read fp32, write bf16 activated features (layers 1-3) ----------------
template <int CO>
__global__ __launch_bounds__(256) void k_bn_elu(const float* __restrict__ h, const float* __restrict__ stats,
                                                unsigned short* __restrict__ hb, int N) {
    __shared__ float sc[CO], sh[CO];
    if (threadIdx.x < CO) {
        sc[threadIdx.x] = stats[128 + threadIdx.x];
        sh[threadIdx.x] = stats[192 + threadIdx.x];
    }
    __syncthreads();
    int total = N * (CO / 4);
    int i = blockIdx.x * 256 + threadIdx.x;
    if (i >= total) return;
    float4 v = ((const float4*)h)[i];
    int cq = (i % (CO / 4)) * 4;
    v.x = v.x * sc[cq + 0] + sh[cq + 0];
    v.y = v.y * sc[cq + 1] + sh[cq + 1];
    v.z = v.z * sc[cq + 2] + sh[cq + 2];
    v.w = v.w * sc[cq + 3] + sh[cq + 3];
    v.x = v.x > 0.f ? v.x : expm1f(v.x);
    v.y = v.y > 0.f ? v.y : expm1f(v.y);
    v.z = v.z > 0.f ? v.z : expm1f(v.z);
    v.w = v.w > 0.f ? v.w : expm1f(v.w);
    ushort4 o;
    o.x = f2bf(v.x); o.y = f2bf(v.y); o.z = f2bf(v.z); o.w = f2bf(v.w);
    ((ushort4*)hb)[i] = o;
}

// ---------------- layer 4: BN + ELU + global mean pool + head fused (last-block runs the head) ----------------
__global__ __launch_bounds__(256) void k_bn_elu_pool_head(const float* __restrict__ h, const float* __restrict__ stats,
                                                          const int* __restrict__ batch,
                                                          float* __restrict__ pooled, float* __restrict__ cntg,
                                                          int* __restrict__ cnt,
                                                          const float* __restrict__ w1, const float* __restrict__ b1,
                                                          const float* __restrict__ w2, const float* __restrict__ b2,
                                                          float* __restrict__ out, int N) {
    __shared__ int is_last;
    int lane = threadIdx.x & 63;  // lane == channel
    int wid = blockIdx.x * 4 + (threadIdx.x >> 6);
    int n0 = wid * 16;
    if (n0 < N) {
        float scl = stats[128 + lane];
        float shl = stats[192 + lane];
        int nmax = N - n0; if (nmax > 16) nmax = 16;
        int cur = batch[n0];
        float acc = 0.f;
        float run = 0.f;
        for (int k = 0; k < nmax; k++) {
            int g = batch[n0 + k];
            if (g != cur) {
                atomicAdd(&pooled[(size_t)cur * 64 + lane], acc);
                if (lane == 0) atomicAdd(&cntg[cur], run);
                cur = g; acc = 0.f; run = 0.f;
            }
            float v = h[(size_t)(n0 + k) * 64 + lane] * scl + shl;
            v = v > 0.f ? v : expm1f(v);
            acc += v;
            run += 1.f;
        }
        atomicAdd(&pooled[(size_t)cur * 64 + lane], acc);
        if (lane == 0) atomicAdd(&cntg[cur], run);
    }
    __threadfence();
    __syncthreads();
    if (threadIdx.x == 0) is_last = (atomicAdd(cnt, 1) == (int)gridDim.x - 1);
    __syncthreads();
    if (!is_last) return;
    __threadfence();
    // ---- head: 256 threads == 256 graphs ----
    int g = threadIdx.x;
    float rec = 1.0f / fmaxf(cntg[g], 1.0f);
    float p[64];
    {
        const float4* pp = (const float4*)(pooled + (size_t)g * 64);
#pragma unroll
        for (int i = 0; i < 16; i++) {
            float4 v = pp[i];
            p[4 * i + 0] = v.x * rec; p[4 * i + 1] = v.y * rec;
            p[4 * i + 2] = v.z * rec; p[4 * i + 3] = v.w * rec;
        }
    }
    float lg[10];
#pragma unroll
    for (int t = 0; t < 10; t++) lg[t] = b2[t];
#pragma unroll 1
    for (int j = 0; j < 64; j++) {
        float a = b1[j];
#pragma unroll
        for (int k = 0; k < 64; k++) a += p[k] * w1[k * 64 + j];  // uniform -> s_load
        a = fmaxf(a, 0.f);
#pragma unroll
        for (int t = 0; t < 10; t++) lg[t] += a * w2[j * 10 + t];
    }
    float m = -1e30f;
#pragma unroll
    for (int t = 0; t < 10; t++) m = fmaxf(m, lg[t]);
    float s = 0.f;
#pragma unroll
    for (int t = 0; t < 10; t++) s += expf(lg[t] - m);
    float lse = m + logf(s);
#pragma unroll
    for (int t = 0; t < 10; t++) out[(size_t)g * 10 + t] = lg[t] - lse;
}

extern "C" void kernel_launch(void* const* d_in, const int* in_sizes, int n_in,
                              void* d_out, int out_size, void* d_ws, size_t ws_size,
                              hipStream_t stream) {
    const float* x = (const float*)d_in[0];
    const int* ei = (const int*)d_in[1];
    const int* batch = (const int*)d_in[2];
    const int N = in_sizes[0] / 64;
    const int E = in_sizes[1] / 2;
    const int* src = ei;
    const int* dst = ei + E;

    const float* w_rel1 = (const float*)d_in[3];
    const float* w_root1 = (const float*)d_in[4];
    const float* b1 = (const float*)d_in[5];
    const float* g1 = (const float*)d_in[6];
    const float* be1 = (const float*)d_in[7];
    const float* w_rel2 = (const float*)d_in[8];
    const float* w_root2 = (const float*)d_in[9];
    const float* b2 = (const float*)d_in[10];
    const float* g2 = (const float*)d_in[11];
    const float* be2 = (const float*)d_in[12];
    const float* w_rel3 = (const float*)d_in[13];
    const float* w_root3 = (const float*)d_in[14];
    const float* b3 = (const float*)d_in[15];
    const float* g3 = (const float*)d_in[16];
    const float* be3 = (const float*)d_in[17];
    const float* w_rel4 = (const float*)d_in[18];
    const float* w_root4 = (const float*)d_in[19];
    const float* b4 = (const float*)d_in[20];
    const float* g4 = (const float*)d_in[21];
    const float* be4 = (const float*)d_in[22];
    const float* w_lin1 = (const float*)d_in[23];
    const float* b_lin1 = (const float*)d_in[24];
    const float* w_lin2 = (const float*)d_in[25];
    const float* b_lin2 = (const float*)d_in[26];

    char* ws = (char*)d_ws;
    size_t off = 0;
    auto alloc = [&](size_t bytes) { size_t o = off; off += (bytes + 255) & ~(size_t)255; return o; };
    int* hmat = (int*)(ws + alloc((size_t)NSORT * NBUCK * 4));
    int* bstart = (int*)(ws + alloc((size_t)(NBUCK + 1) * 4));
    unsigned* ebuf = (unsigned*)(ws + alloc((size_t)E * 4));
    int* csr = (int*)(ws + alloc((size_t)E * 4));
    int* row_start = (int*)(ws + alloc((size_t)(N + 1) * 4));
    float* agg = (float*)(ws + alloc((size_t)N * 32 * 4));
    unsigned short* y1b = (unsigned short*)(ws + alloc((size_t)N * 16 * 2));
    unsigned short* hb = (unsigned short*)(ws + alloc((size_t)N * 64 * 2));
    float* bufA = (float*)(ws + alloc((size_t)N * 64 * 4));
    float* stats = (float*)(ws + alloc(4 * 256 * 4));
    float* partials = (float*)(ws + alloc((size_t)LSTAT * 128 * 4));
    float* pooled = (float*)(ws + alloc((size_t)(NGRAPHS * 64 + NGRAPHS + 8) * 4));
    float* cntg = pooled + NGRAPHS * 64;
    int* cnt = (int*)(cntg + NGRAPHS);
    const int zwords = NGRAPHS * 64 + NGRAPHS + 8;  // pooled + cntg + cnt[8]

    const float invN = 1.0f / (float)N;
    const int gbl = (N + 3) / 4;  // gather: 4 waves/block, 1 wave/node

    // ---- CSR build (4 dispatches): bhist (+zero-init), merged scan, scatter, sort ----
    k_bhist<<<NSORT, 256, 0, stream>>>(dst, hmat, E, pooled, zwords);
    k_scan<<<1, 512, 0, stream>>>(hmat, bstart);
    k_bscatter<<<NSORT, 256, 0, stream>>>(src, dst, hmat, bstart, ebuf, E);
    k_sort2<<<NBUCK, 256, 0, stream>>>(ebuf, bstart, csr, row_start, N);

    // ---- Layer 1 (64 -> 16): rel matmul (bf16 out), gather16, root-lin + fused stats, bn_elu ----
    k_lin_rel<64, 16><<<(N * 4 + 255) / 256, 256, 0, stream>>>(x, w_rel1, y1b, N);
    k_gather<16><<<gbl, 256, 0, stream>>>(y1b, row_start, csr, agg, N);
    k_lin_stats<64, 16, false, true, false><<<LSTAT, 256, 0, stream>>>(
        x, nullptr, nullptr, w_root1, b1, agg, bufA, partials, g1, be1, stats + 0, cnt + 0, invN, N);
    k_bn_elu<16><<<(N * 4 + 255) / 256, 256, 0, stream>>>(bufA, stats + 0, hb, N);

    // ---- Layer 2 (16 -> 32) ----
    k_gather<16><<<gbl, 256, 0, stream>>>(hb, row_start, csr, agg, N);
    k_lin_stats<16, 32, true, false, true><<<LSTAT, 256, 0, stream>>>(
        hb, agg, w_rel2, w_root2, b2, nullptr, bufA, partials, g2, be2, stats + 256, cnt + 1, invN, N);
    k_bn_elu<32><<<(N * 8 + 255) / 256, 256, 0, stream>>>(bufA, stats + 256, hb, N);

    // ---- Layer 3 (32 -> 32) ----
    k_gather<32><<<gbl, 256, 0, stream>>>(hb, row_start, csr, agg, N);
    k_lin_stats<32, 32, true, false, true><<<LSTAT, 256, 0, stream>>>(
        hb, agg, w_rel3, w_root3, b3, nullptr, bufA, partials, g3, be3, stats + 512, cnt + 2, invN, N);
    k_bn_elu<32><<<(N * 8 + 255) / 256, 256, 0, stream>>>(bufA, stats + 512, hb, N);

    // ---- Layer 4 (32 -> 64): gather, lin + stats, fused BN+ELU+pool+head ----
    k_gather<32><<<gbl, 256, 0, stream>>>(hb, row_start, csr, agg, N);
    k_lin_stats<32, 64, true, false, true><<<LSTAT, 256, 0, stream>>>(
        hb, agg, w_rel4, w_root4, b4, nullptr, bufA, partials, g4, be4, stats + 768, cnt + 3, invN, N);
    int waves16 = (N + 15) / 16;
    k_bn_elu_pool_head<<<(waves16 + 3) / 4, 256, 0, stream>>>(
        bufA, stats + 768, batch, pooled, cntg, cnt + 4, w_lin1, b_lin1, w_lin2, b_lin2, (float*)d_out, N);
}